// Round 4
// baseline (511.591 us; speedup 1.0000x reference)
//
#include <hip/hip_runtime.h>

typedef unsigned int uint;
typedef unsigned short ushort;
typedef unsigned long long u64;
typedef float f32x4 __attribute__((ext_vector_type(4)));
typedef float f32x2 __attribute__((ext_vector_type(2)));

#define NN 100000
#define NE 1600000
#define SCAN_BLK 256
#define NBLK ((NN + SCAN_BLK - 1) / SCAN_BLK)   // 391

// ---- bf16 helpers (RTNE, finite values only) ------------------------------
__device__ __forceinline__ ushort f2bf(float f) {
    uint u = __float_as_uint(f);
    u += 0x7FFFu + ((u >> 16) & 1u);
    return (ushort)(u >> 16);
}
__device__ __forceinline__ float bf2f(ushort h) {
    return __uint_as_float(((uint)h) << 16);
}

// ---------------------------------------------------------------------------
// GEMM: Y[N,M](bf16) = act(X[N,128]) @ W[128,M] + b    (act=relu if RELU_IN)
// X is f32; streaming loads/stores are nontemporal to preserve L2 for spmm.
// ---------------------------------------------------------------------------
template <int M, int ROWS, bool RELU_IN>
__global__ __launch_bounds__(256) void gemm_kernel(
    const float* __restrict__ X, const float* __restrict__ W,
    const float* __restrict__ b, ushort* __restrict__ Y, int N)
{
    constexpr int K  = 128;
    constexpr int CG = M / 4;        // col groups (4 cols each)
    constexpr int RG = 256 / CG;     // row groups
    constexpr int RPT = ROWS / RG;   // rows per thread
    static_assert(RPT == 4, "expect 4 rows per thread");

    __shared__ float xt[K * ROWS];   // [k][r]  (transposed)
    __shared__ float Ws[64 * M];     // half of W: [kk][m]

    const int tid  = threadIdx.x;
    const int row0 = blockIdx.x * ROWS;

    for (int i = tid; i < ROWS * (K / 4); i += 256) {
        int r  = i % ROWS;
        int k4 = i / ROWS;
        int rr = row0 + r;
        if (rr >= N) rr = N - 1;               // clamp (stores are guarded)
        f32x4 v = __builtin_nontemporal_load(
            reinterpret_cast<const f32x4*>(X) + rr * (K / 4) + k4);
        if (RELU_IN) {
            v.x = fmaxf(v.x, 0.f); v.y = fmaxf(v.y, 0.f);
            v.z = fmaxf(v.z, 0.f); v.w = fmaxf(v.w, 0.f);
        }
        xt[(k4 * 4 + 0) * ROWS + r] = v.x;
        xt[(k4 * 4 + 1) * ROWS + r] = v.y;
        xt[(k4 * 4 + 2) * ROWS + r] = v.z;
        xt[(k4 * 4 + 3) * ROWS + r] = v.w;
    }

    const int cg = tid % CG;
    const int rg = tid / CG;
    const int c0 = cg * 4;
    const int r0 = rg * RPT;

    float acc[4][4];
    {
        float4 bv = reinterpret_cast<const float4*>(b)[cg];
        #pragma unroll
        for (int i = 0; i < 4; ++i) {
            acc[i][0] = bv.x; acc[i][1] = bv.y; acc[i][2] = bv.z; acc[i][3] = bv.w;
        }
    }

    for (int kh = 0; kh < 2; ++kh) {
        __syncthreads();
        for (int i = tid; i < 64 * (M / 4); i += 256) {
            reinterpret_cast<float4*>(Ws)[i] =
                reinterpret_cast<const float4*>(W)[kh * 64 * (M / 4) + i];
        }
        __syncthreads();

        #pragma unroll 4
        for (int kk = 0; kk < 64; ++kk) {
            const int k = kh * 64 + kk;
            float4 xv = *reinterpret_cast<const float4*>(&xt[k * ROWS + r0]);
            float4 wv = *reinterpret_cast<const float4*>(&Ws[kk * M + c0]);
            acc[0][0] += xv.x * wv.x; acc[0][1] += xv.x * wv.y;
            acc[0][2] += xv.x * wv.z; acc[0][3] += xv.x * wv.w;
            acc[1][0] += xv.y * wv.x; acc[1][1] += xv.y * wv.y;
            acc[1][2] += xv.y * wv.z; acc[1][3] += xv.y * wv.w;
            acc[2][0] += xv.z * wv.x; acc[2][1] += xv.z * wv.y;
            acc[2][2] += xv.z * wv.z; acc[2][3] += xv.z * wv.w;
            acc[3][0] += xv.w * wv.x; acc[3][1] += xv.w * wv.y;
            acc[3][2] += xv.w * wv.z; acc[3][3] += xv.w * wv.w;
        }
    }

    #pragma unroll
    for (int i = 0; i < 4; ++i) {
        int rr = row0 + r0 + i;
        if (rr < N) {
            u64 o = (u64)f2bf(acc[i][0])
                  | ((u64)f2bf(acc[i][1]) << 16)
                  | ((u64)f2bf(acc[i][2]) << 32)
                  | ((u64)f2bf(acc[i][3]) << 48);
            __builtin_nontemporal_store(o, reinterpret_cast<u64*>(&Y[rr * M + c0]));
        }
    }
}

// ---------------------------------------------------------------------------
// CSR build
// ---------------------------------------------------------------------------
__global__ __launch_bounds__(256) void hist_kernel(
    const int* __restrict__ rows, int* __restrict__ counts)
{
    int t = blockIdx.x * 256 + threadIdx.x;
    if (t < NE / 4) {
        int4 r = reinterpret_cast<const int4*>(rows)[t];
        atomicAdd(&counts[r.x], 1); atomicAdd(&counts[r.y], 1);
        atomicAdd(&counts[r.z], 1); atomicAdd(&counts[r.w], 1);
    }
}

// Per-block scan: row_ptr[i] = exclusive prefix (partial), counts[i] = inclusive
// prefix (partial, becomes the bucket END pointer after base add).
__global__ __launch_bounds__(SCAN_BLK) void scan_block_kernel(
    int* __restrict__ counts, int* __restrict__ row_ptr, int* __restrict__ bsums)
{
    __shared__ int s[SCAN_BLK];
    const int tid = threadIdx.x;
    const int i   = blockIdx.x * SCAN_BLK + tid;
    int v = (i < NN) ? counts[i] : 0;
    s[tid] = v;
    __syncthreads();
    for (int off = 1; off < SCAN_BLK; off <<= 1) {
        int t = (tid >= off) ? s[tid - off] : 0;
        __syncthreads();
        s[tid] += t;
        __syncthreads();
    }
    if (i < NN) {
        row_ptr[i] = s[tid] - v;     // exclusive, no base
        counts[i]  = s[tid];         // inclusive, no base (end pointer)
    }
    if (tid == SCAN_BLK - 1) bsums[blockIdx.x] = s[tid];
}

__global__ __launch_bounds__(512) void scan_sums_kernel(int* __restrict__ bsums)
{
    __shared__ int s[512];
    const int tid = threadIdx.x;
    int v = (tid < NBLK) ? bsums[tid] : 0;
    s[tid] = v;
    __syncthreads();
    for (int off = 1; off < 512; off <<= 1) {
        int t = (tid >= off) ? s[tid - off] : 0;
        __syncthreads();
        s[tid] += t;
        __syncthreads();
    }
    if (tid < NBLK) bsums[tid] = s[tid] - v;      // exclusive
}

__global__ __launch_bounds__(SCAN_BLK) void add_base_kernel(
    int* __restrict__ row_ptr, int* __restrict__ counts,
    const int* __restrict__ bsums)
{
    const int i = blockIdx.x * SCAN_BLK + threadIdx.x;
    if (i < NN) {
        int base = bsums[blockIdx.x];
        row_ptr[i] += base;
        counts[i]  += base;          // now = row end pointer
    } else if (i == NN) {
        row_ptr[NN] = NE;
    }
}

// scatter: pos = --end[r]; es[pos] = {col | val_bits<<32}. 1 edge/thread
// (latency-bound: maximize independent atomic chains in flight).
__global__ __launch_bounds__(256) void scatter_edges_kernel(
    const int* __restrict__ rows, const int* __restrict__ cols,
    const float* __restrict__ vals, int* __restrict__ endp,
    u64* __restrict__ es)
{
    int e = blockIdx.x * 256 + threadIdx.x;
    if (e >= NE) return;
    const int   r = rows[e];
    const int   c = cols[e];
    const float v = vals[e];
    int p = atomicSub(&endp[r], 1) - 1;
    u64 packed = (u64)(uint)c | ((u64)(uint)__float_as_uint(v) << 32);
    __builtin_nontemporal_store(packed, &es[p]);
}

// ---------------------------------------------------------------------------
// Gather spmm: one wave per row; bf16 Z rows; f32 accumulate; f32 out.
// 8-deep unroll keeps 8 independent gathers in flight per wave.
// ---------------------------------------------------------------------------
template <int D>
__global__ __launch_bounds__(256) void spmm_gather(
    const int* __restrict__ row_ptr, const u64* __restrict__ es,
    const ushort* __restrict__ Zb, float* __restrict__ out)
{
    const int row  = (blockIdx.x * 256 + threadIdx.x) >> 6;
    const int lane = threadIdx.x & 63;
    if (row >= NN) return;
    const int start = row_ptr[row];
    const int end   = row_ptr[row + 1];

    float accx = 0.f, accy = 0.f;

    for (int base = start; base < end; base += 64) {
        const int m = min(end - base, 64);
        int c = 0, vb = 0;
        if (lane < m) {
            u64 e = __builtin_nontemporal_load(&es[base + lane]);
            c  = (int)(uint)(e & 0xFFFFFFFFu);
            vb = (int)(uint)(e >> 32);
        }

        int j = 0;
        for (; j + 8 <= m; j += 8) {
            int cc[8]; float vv[8];
            #pragma unroll
            for (int q = 0; q < 8; ++q) {
                cc[q] = __shfl(c, j + q);
                vv[q] = __int_as_float(__shfl(vb, j + q));
            }
            if (D == 128) {
                uint z[8];
                #pragma unroll
                for (int q = 0; q < 8; ++q)
                    z[q] = *reinterpret_cast<const uint*>(&Zb[(size_t)cc[q] * 128 + 2 * lane]);
                #pragma unroll
                for (int q = 0; q < 8; ++q) {
                    accx += vv[q] * __uint_as_float(z[q] << 16);
                    accy += vv[q] * __uint_as_float(z[q] & 0xFFFF0000u);
                }
            } else {
                float z[8];
                #pragma unroll
                for (int q = 0; q < 8; ++q)
                    z[q] = bf2f(Zb[(size_t)cc[q] * 64 + lane]);
                #pragma unroll
                for (int q = 0; q < 8; ++q)
                    accx += vv[q] * z[q];
            }
        }
        for (; j + 4 <= m; j += 4) {
            int cc[4]; float vv[4];
            #pragma unroll
            for (int q = 0; q < 4; ++q) {
                cc[q] = __shfl(c, j + q);
                vv[q] = __int_as_float(__shfl(vb, j + q));
            }
            if (D == 128) {
                #pragma unroll
                for (int q = 0; q < 4; ++q) {
                    uint z = *reinterpret_cast<const uint*>(&Zb[(size_t)cc[q] * 128 + 2 * lane]);
                    accx += vv[q] * __uint_as_float(z << 16);
                    accy += vv[q] * __uint_as_float(z & 0xFFFF0000u);
                }
            } else {
                #pragma unroll
                for (int q = 0; q < 4; ++q)
                    accx += vv[q] * bf2f(Zb[(size_t)cc[q] * 64 + lane]);
            }
        }
        for (; j < m; ++j) {
            int   cj = __shfl(c, j);
            float vj = __int_as_float(__shfl(vb, j));
            if (D == 128) {
                uint z = *reinterpret_cast<const uint*>(&Zb[(size_t)cj * 128 + 2 * lane]);
                accx += vj * __uint_as_float(z << 16);
                accy += vj * __uint_as_float(z & 0xFFFF0000u);
            } else {
                accx += vj * bf2f(Zb[(size_t)cj * 64 + lane]);
            }
        }
    }

    if (D == 128) {
        f32x2 o; o.x = accx; o.y = accy;
        __builtin_nontemporal_store(o,
            reinterpret_cast<f32x2*>(&out[(size_t)row * 128 + 2 * lane]));
    } else {
        __builtin_nontemporal_store(accx, &out[(size_t)row * 64 + lane]);
    }
}

// ---------------------------------------------------------------------------
extern "C" void kernel_launch(void* const* d_in, const int* in_sizes, int n_in,
                              void* d_out, int out_size, void* d_ws, size_t ws_size,
                              hipStream_t stream)
{
    const int*   rows = (const int*)  d_in[0];
    const int*   cols = (const int*)  d_in[1];
    const float* vals = (const float*)d_in[2];
    const float* x    = (const float*)d_in[3];
    const float* W1   = (const float*)d_in[4];
    const float* b1   = (const float*)d_in[5];
    const float* W2   = (const float*)d_in[6];
    const float* b2   = (const float*)d_in[7];
    float* out = (float*)d_out;

    char* ws = (char*)d_ws;
    size_t off = 0;
    ushort* h1b    = (ushort*)(ws + off); off += (size_t)NN * 128 * sizeof(ushort); // 25.6MB
    float*  s1     = (float*) (ws + off); off += (size_t)NN * 128 * sizeof(float);  // 51.2MB
    ushort* h2b    = (ushort*)(ws + off); off += (size_t)NN * 64 * sizeof(ushort);  // 12.8MB
    u64*    es     = (u64*)   (ws + off); off += (size_t)NE * sizeof(u64);          // 12.8MB
    int*    row_ptr= (int*)   (ws + off); off += (size_t)(NN + 1) * sizeof(int);
    int*    counts = (int*)   (ws + off); off += (size_t)NN * sizeof(int);
    int*    bsums  = (int*)   (ws + off); off += (size_t)NBLK * sizeof(int);
    // total ~103 MB

    // ---- CSR build (A shared by both layers) ----
    hipMemsetAsync(counts, 0, (size_t)NN * sizeof(int), stream);
    hist_kernel<<<(NE / 4 + 255) / 256, 256, 0, stream>>>(rows, counts);
    scan_block_kernel<<<NBLK, SCAN_BLK, 0, stream>>>(counts, row_ptr, bsums);
    scan_sums_kernel<<<1, 512, 0, stream>>>(bsums);
    add_base_kernel<<<NBLK, SCAN_BLK, 0, stream>>>(row_ptr, counts, bsums);
    scatter_edges_kernel<<<(NE + 255) / 256, 256, 0, stream>>>(
        rows, cols, vals, counts, es);

    // ---- layer 1 ----
    gemm_kernel<128, 32, false><<<NN / 32, 256, 0, stream>>>(x, W1, b1, h1b, NN);
    spmm_gather<128><<<(NN * 64 + 255) / 256, 256, 0, stream>>>(row_ptr, es, h1b, s1);

    // ---- layer 2 ----  (relu fused into gemm2 staging; s1 stays f32)
    gemm_kernel<64, 64, true><<<(NN + 63) / 64, 256, 0, stream>>>(s1, W2, b2, h2b, NN);
    spmm_gather<64><<<(NN * 64 + 255) / 256, 256, 0, stream>>>(row_ptr, es, h2b, out);
}